// Round 9
// baseline (474.112 us; speedup 1.0000x reference)
//
#include <hip/hip_runtime.h>

#define NTOT 12288
#define NE   196608
#define MAXDEG 64

typedef __attribute__((ext_vector_type(8))) short bf8_t;   // 8 bf16 (4 VGPRs)
typedef __attribute__((ext_vector_type(4))) float f32x4;   // MFMA C/D frag

// turn-local row r (0..2047) of turn t -> global node id
__device__ __forceinline__ int turn_row_map(int r, int t) {
  return (r >> 7) * 768 + t * 128 + (r & 127);
}

// split fp32 into bf16 hi (truncate) + bf16 lo (truncated residual): ~2^-16 rel
__device__ __forceinline__ void splitbf(float x, unsigned short& hi, unsigned short& lo) {
  unsigned u = __float_as_uint(x);
  hi = (unsigned short)(u >> 16);
  float fh = __uint_as_float(u & 0xFFFF0000u);
  lo = (unsigned short)(__float_as_uint(x - fh) >> 16);
}
__device__ __forceinline__ uint2 pack4(unsigned short a, unsigned short b,
                                       unsigned short c, unsigned short d) {
  return make_uint2((unsigned)a | ((unsigned)b << 16), (unsigned)c | ((unsigned)d << 16));
}

// ---------------- fused prologue: feat | wconv | adj (after cnt memset) ----------------
__global__ void __launch_bounds__(256)
k_prep(const float* __restrict__ emb, const float* __restrict__ nmask,
       const int* __restrict__ nodeidx,
       const float* __restrict__ W, const float* __restrict__ Wz,
       const float* __restrict__ Wr, const float* __restrict__ Wn,
       const float* __restrict__ Uz, const float* __restrict__ Ur,
       const float* __restrict__ Un,
       const int* __restrict__ esrc, const int* __restrict__ edst, int* __restrict__ cnt,
       float* __restrict__ h, unsigned short* __restrict__ hbh,
       unsigned short* __restrict__ hbl,
       unsigned short* __restrict__ wth, unsigned short* __restrict__ wtl,
       unsigned short* __restrict__ adj) {
  int l = blockIdx.x, tid = threadIdx.x;
  if (l < 3072) {            // ---- feat: NTOT*64 float4 + bf planes ----
    int i = l * 256 + tid;
    int row = i >> 6;
    int src = nodeidx[row];
    float m = nmask[src];
    float4 v = ((const float4*)emb)[(size_t)src * 64 + (i & 63)];
    v.x *= m; v.y *= m; v.z *= m; v.w *= m;
    ((float4*)h)[i] = v;
    unsigned short h0,l0,h1,l1,h2,l2,h3,l3;
    splitbf(v.x,h0,l0); splitbf(v.y,h1,l1); splitbf(v.z,h2,l2); splitbf(v.w,h3,l3);
    int o = row * 256 + (i & 63) * 4;
    *(uint2*)(hbh + o) = pack4(h0,h1,h2,h3);
    *(uint2*)(hbl + o) = pack4(l0,l1,l2,l3);
  } else if (l < 4864) {     // ---- wconv: weights -> transposed hi/lo planes ----
    // rows (n-major, k contiguous): [0,256)=W | [256,1024)=Wz,Wr,Wn | [1024,1536)=Uz,Ur | [1536,1792)=Un
    int idx = (l - 3072) * 256 + tid;
    int n = idx >> 8, k = idx & 255;
    float v;
    if (n < 256) v = W[k * 256 + n];
    else if (n < 1024) { int g=(n-256)>>8, c=(n-256)&255; v = (g==0?Wz:g==1?Wr:Wn)[k*256+c]; }
    else if (n < 1536) { int g=(n-1024)>>8, c=(n-1024)&255; v = (g==0?Uz:Ur)[k*256+c]; }
    else v = Un[k * 256 + (n - 1536)];
    unsigned short hh, ll; splitbf(v, hh, ll);
    wth[idx] = hh; wtl[idx] = ll;
  } else {                   // ---- adj: padded adjacency ----
    int e = (l - 4864) * 256 + tid;
    int d = edst[e];
    int pos = atomicAdd(&cnt[d], 1);
    if (pos < MAXDEG) adj[(size_t)d * MAXDEG + pos] = (unsigned short)esrc[e];
  }
}

// -------- split-bf16 MFMA GEMM: 32x128 block, 4 waves, 2x2 tiles/wave, dbuf --------
// MODE 5: blocks [0,768) full Wh=h@W + es/ed; blocks [768,1536) uacc batch q=0
// MODE 1: whup rows of turn t (A=h planes via map), Wh + es/ed     grid 128
// MODE 2: gates (A=msg planes), epilogue z/rh/npre                 grid 384
// MODE 3: gru (A=rh planes, B=Un), epilogue -> h fp32+planes       grid 128
// MODE 4: uacc batch q=1                                           grid 768
template <int MODE>
__global__ void __launch_bounds__(256)
k_mf(const unsigned short* __restrict__ aph, const unsigned short* __restrict__ apl,
     const unsigned short* __restrict__ wth, const unsigned short* __restrict__ wtl,
     float* __restrict__ Wh, float* __restrict__ hbuf,
     unsigned short* __restrict__ hbh, unsigned short* __restrict__ hbl,
     float* __restrict__ g1, float* __restrict__ uacc,
     unsigned short* __restrict__ rbh, unsigned short* __restrict__ rbl,
     const float* __restrict__ bz, const float* __restrict__ br,
     const float* __restrict__ bn,
     const float* __restrict__ asrc, const float* __restrict__ adst,
     float* __restrict__ es, float* __restrict__ ed, int t) {
  __shared__ __align__(16) unsigned short Ah[2][32][40], Al[2][32][40];
  __shared__ __align__(16) unsigned short Bh[2][128][40], Bl[2][128][40];
  __shared__ float esb[32][4], edb[32][4];
  int l = blockIdx.x;
  bool m0 = true;
  int bx, by;
  if constexpr (MODE == 5) {
    if (l < 768) { bx = (l & 15) >> 3; by = (l >> 4) * 8 + (l & 7); }
    else { m0 = false; int l2 = l - 768; bx = (l2 & 31) >> 3; by = (l2 >> 5) * 8 + (l2 & 7); }
  } else if constexpr (MODE == 2) { bx = (l % 48) >> 3; by = (l / 48) * 8 + (l & 7); }
  else if constexpr (MODE == 4)   { bx = (l & 31) >> 3; by = (l >> 5) * 8 + (l & 7); }
  else                            { bx = (l & 15) >> 3; by = (l >> 4) * 8 + (l & 7); }

  int tid = threadIdx.x;
  int ar = tid >> 3, aq = tid & 7;        // A staging: 32 rows x 8 uint2
  int brow = tid >> 1, bhalf = tid & 1;   // B staging: 128 rows x 2 halves
  int gmA = by * 32 + ar;
  int arow;
  if constexpr (MODE == 1) arow = turn_row_map(gmA, t);
  else if constexpr (MODE == 5)
    arow = m0 ? gmA : (gmA / 384) * 768 + ((gmA % 384) >> 7) * 128 + (gmA & 127);
  else if constexpr (MODE == 4)
    arow = (gmA / 384) * 768 + (3 + ((gmA % 384) >> 7)) * 128 + (gmA & 127);
  else arow = gmA;  // MODE 2 (msg planes), MODE 3 (rh planes)
  const unsigned short* ahp = aph + (size_t)arow * 256;
  const unsigned short* alp = apl + (size_t)arow * 256;

  int nbase;
  if constexpr (MODE == 5)      nbase = m0 ? bx * 128 : 1024 + bx * 128;
  else if constexpr (MODE == 1) nbase = bx * 128;
  else if constexpr (MODE == 2) nbase = 256 + bx * 128;
  else if constexpr (MODE == 3) nbase = 1536 + bx * 128;
  else                          nbase = 1024 + bx * 128;
  const unsigned short* bhp = wth + (size_t)(nbase + brow) * 256 + bhalf * 16;
  const unsigned short* blp = wtl + (size_t)(nbase + brow) * 256 + bhalf * 16;

  uint2 rah, ral; uint4 rb0h, rb1h, rb0l, rb1l;
  auto loadc = [&](int c) {
    int k0 = c * 32;
    rah = *(const uint2*)(ahp + k0 + aq * 4);
    ral = *(const uint2*)(alp + k0 + aq * 4);
    rb0h = *(const uint4*)(bhp + k0);
    rb1h = *(const uint4*)(bhp + k0 + 8);
    rb0l = *(const uint4*)(blp + k0);
    rb1l = *(const uint4*)(blp + k0 + 8);
  };
  auto storec = [&](int b) {
    *(uint2*)&Ah[b][ar][aq * 4] = rah;
    *(uint2*)&Al[b][ar][aq * 4] = ral;
    *(uint4*)&Bh[b][brow][bhalf * 16] = rb0h;
    *(uint4*)&Bh[b][brow][bhalf * 16 + 8] = rb1h;
    *(uint4*)&Bl[b][brow][bhalf * 16] = rb0l;
    *(uint4*)&Bl[b][brow][bhalf * 16 + 8] = rb1l;
  };

  int lane = tid & 63, wv = tid >> 6;
  int quad = lane >> 4, nl = lane & 15;
  f32x4 acc[2][2] = {{{0.f,0.f,0.f,0.f},{0.f,0.f,0.f,0.f}},
                     {{0.f,0.f,0.f,0.f},{0.f,0.f,0.f,0.f}}};
  loadc(0); storec(0); __syncthreads();
  for (int c = 0; c < 8; c++) {
    int cur = c & 1;
    if (c < 7) loadc(c + 1);
    bf8_t a_h0 = *(const bf8_t*)&Ah[cur][nl][quad * 8];
    bf8_t a_h1 = *(const bf8_t*)&Ah[cur][16 + nl][quad * 8];
    bf8_t a_l0 = *(const bf8_t*)&Al[cur][nl][quad * 8];
    bf8_t a_l1 = *(const bf8_t*)&Al[cur][16 + nl][quad * 8];
    bf8_t b_h0 = *(const bf8_t*)&Bh[cur][wv * 32 + nl][quad * 8];
    bf8_t b_h1 = *(const bf8_t*)&Bh[cur][wv * 32 + 16 + nl][quad * 8];
    bf8_t b_l0 = *(const bf8_t*)&Bl[cur][wv * 32 + nl][quad * 8];
    bf8_t b_l1 = *(const bf8_t*)&Bl[cur][wv * 32 + 16 + nl][quad * 8];
    acc[0][0] = __builtin_amdgcn_mfma_f32_16x16x32_bf16(a_h0, b_h0, acc[0][0], 0, 0, 0);
    acc[0][1] = __builtin_amdgcn_mfma_f32_16x16x32_bf16(a_h0, b_h1, acc[0][1], 0, 0, 0);
    acc[1][0] = __builtin_amdgcn_mfma_f32_16x16x32_bf16(a_h1, b_h0, acc[1][0], 0, 0, 0);
    acc[1][1] = __builtin_amdgcn_mfma_f32_16x16x32_bf16(a_h1, b_h1, acc[1][1], 0, 0, 0);
    acc[0][0] = __builtin_amdgcn_mfma_f32_16x16x32_bf16(a_h0, b_l0, acc[0][0], 0, 0, 0);
    acc[0][1] = __builtin_amdgcn_mfma_f32_16x16x32_bf16(a_h0, b_l1, acc[0][1], 0, 0, 0);
    acc[1][0] = __builtin_amdgcn_mfma_f32_16x16x32_bf16(a_h1, b_l0, acc[1][0], 0, 0, 0);
    acc[1][1] = __builtin_amdgcn_mfma_f32_16x16x32_bf16(a_h1, b_l1, acc[1][1], 0, 0, 0);
    acc[0][0] = __builtin_amdgcn_mfma_f32_16x16x32_bf16(a_l0, b_h0, acc[0][0], 0, 0, 0);
    acc[0][1] = __builtin_amdgcn_mfma_f32_16x16x32_bf16(a_l0, b_h1, acc[0][1], 0, 0, 0);
    acc[1][0] = __builtin_amdgcn_mfma_f32_16x16x32_bf16(a_l1, b_h0, acc[1][0], 0, 0, 0);
    acc[1][1] = __builtin_amdgcn_mfma_f32_16x16x32_bf16(a_l1, b_h1, acc[1][1], 0, 0, 0);
    if (c < 7) storec(cur ^ 1);
    __syncthreads();
  }

  // D layout per tile (rt,ct): row = by*32 + rt*16 + quad*4 + r ; col = base + ct*16 + nl
  auto wh_es_epi = [&](bool mapped) {
    int colbase = bx * 128 + wv * 32;
    float a0 = asrc[colbase + nl], a1 = asrc[colbase + 16 + nl];
    float d0 = adst[colbase + nl], d1 = adst[colbase + 16 + nl];
    float pes[2][4], ped[2][4];
#pragma unroll
    for (int rt = 0; rt < 2; rt++)
#pragma unroll
      for (int r = 0; r < 4; r++) {
        int rloc = by * 32 + rt * 16 + quad * 4 + r;
        int v = mapped ? turn_row_map(rloc, t) : rloc;
        float x0 = acc[rt][0][r], x1 = acc[rt][1][r];
        Wh[(size_t)v * 256 + colbase + nl] = x0;
        Wh[(size_t)v * 256 + colbase + 16 + nl] = x1;
        pes[rt][r] = x0 * a0 + x1 * a1;
        ped[rt][r] = x0 * d0 + x1 * d1;
      }
#pragma unroll
    for (int m = 1; m < 16; m <<= 1)
#pragma unroll
      for (int rt = 0; rt < 2; rt++)
#pragma unroll
        for (int r = 0; r < 4; r++) {
          pes[rt][r] += __shfl_xor(pes[rt][r], m);
          ped[rt][r] += __shfl_xor(ped[rt][r], m);
        }
    if (nl == 0)
#pragma unroll
      for (int rt = 0; rt < 2; rt++)
#pragma unroll
        for (int r = 0; r < 4; r++) {
          esb[rt * 16 + quad * 4 + r][wv] = pes[rt][r];
          edb[rt * 16 + quad * 4 + r][wv] = ped[rt][r];
        }
    __syncthreads();
    if (tid < 32) {
      int m = tid;
      int v = mapped ? turn_row_map(by * 32 + m, t) : (by * 32 + m);
      es[v * 4 + bx * 2 + 0] = esb[m][0] + esb[m][1];
      es[v * 4 + bx * 2 + 1] = esb[m][2] + esb[m][3];
      ed[v * 4 + bx * 2 + 0] = edb[m][0] + edb[m][1];
      ed[v * 4 + bx * 2 + 1] = edb[m][2] + edb[m][3];
    }
  };
  auto uacc_epi = [&]() {
    int cb = bx * 128 + wv * 32;
#pragma unroll
    for (int rt = 0; rt < 2; rt++)
#pragma unroll
      for (int r = 0; r < 4; r++) {
        int grr = by * 32 + rt * 16 + quad * 4 + r;
#pragma unroll
        for (int ct = 0; ct < 2; ct++) {
          float D = acc[rt][ct][r];
          int col = cb + ct * 16 + nl;
          float bias = (col < 256) ? bz[col] : br[col - 256];
          uacc[(size_t)grr * 512 + col] = D + bias;
        }
      }
  };

  if constexpr (MODE == 5) {
    if (m0) wh_es_epi(false); else uacc_epi();
  } else if constexpr (MODE == 1) {
    wh_es_epi(true);
  } else if constexpr (MODE == 2) {
    int g = bx >> 1;
    int cb = (bx & 1) * 128 + wv * 32;
    int tm3 = t % 3;
#pragma unroll
    for (int rt = 0; rt < 2; rt++)
#pragma unroll
      for (int r = 0; r < 4; r++) {
        int rr_ = by * 32 + rt * 16 + quad * 4 + r;
        int v = turn_row_map(rr_, t);
        int urow = (rr_ >> 7) * 384 + tm3 * 128 + (rr_ & 127);
#pragma unroll
        for (int ct = 0; ct < 2; ct++) {
          float D = acc[rt][ct][r];
          int c = cb + ct * 16 + nl;
          if (g == 0) {
            g1[(size_t)rr_ * 512 + c] = D + uacc[(size_t)urow * 512 + c];
          } else if (g == 1) {
            float rpre = D + uacc[(size_t)urow * 512 + 256 + c];
            float rv = 1.f / (1.f + __expf(-rpre));
            float rhv = rv * hbuf[(size_t)v * 256 + c];
            unsigned short hh, ll; splitbf(rhv, hh, ll);
            rbh[rr_ * 256 + c] = hh; rbl[rr_ * 256 + c] = ll;
          } else {
            g1[(size_t)rr_ * 512 + 256 + c] = D + bn[c];
          }
        }
      }
  } else if constexpr (MODE == 3) {
    int cb = bx * 128 + wv * 32;
#pragma unroll
    for (int rt = 0; rt < 2; rt++)
#pragma unroll
      for (int r = 0; r < 4; r++) {
        int rr_ = by * 32 + rt * 16 + quad * 4 + r;
        int v = turn_row_map(rr_, t);
#pragma unroll
        for (int ct = 0; ct < 2; ct++) {
          float D = acc[rt][ct][r];
          int c = cb + ct * 16 + nl;
          float zpre = g1[(size_t)rr_ * 512 + c];
          float npre = g1[(size_t)rr_ * 512 + 256 + c] + D;
          float z = 1.f / (1.f + __expf(-zpre));
          float n = tanhf(npre);
          float hv = hbuf[(size_t)v * 256 + c];
          float hn = (1.f - z) * hv + z * n;
          hbuf[(size_t)v * 256 + c] = hn;
          unsigned short hh, ll; splitbf(hn, hh, ll);
          hbh[v * 256 + c] = hh; hbl[v * 256 + c] = ll;
        }
      }
  } else {  // MODE 4
    uacc_epi();
  }
}

// per-dst attention softmax + message (msg -> bf16 hi/lo planes)
__global__ void k_attn(const int* __restrict__ cnt, const unsigned short* __restrict__ adj,
                       const float* __restrict__ es, const float* __restrict__ ed,
                       const float* __restrict__ Wh,
                       unsigned short* __restrict__ mbh, unsigned short* __restrict__ mbl,
                       float* __restrict__ score, int t, int allnodes) {
  int gph = blockIdx.x & 15, j = blockIdx.x >> 4;
  int w = (allnodes ? gph * 768 : gph * 128) + j * 4 + (threadIdx.x >> 6);
  int lane = threadIdx.x & 63;
  int head = lane >> 4;
  int v, mrow, storemsg;
  if (allnodes) {
    v = w;
    int bt = v >> 7;
    int tt = bt % 6;
    storemsg = (tt == t);
    mrow = (bt / 6) * 128 + (v & 127);
  } else {
    v = turn_row_map(w, t);
    mrow = w;
    storemsg = 1;
  }
  int deg = cnt[v];
  if (deg > MAXDEG) deg = MAXDEG;
  const unsigned short* row = adj + (size_t)v * MAXDEG;
  float edv = ed[v * 4 + head];
  float m = -1e30f;
  for (int jj = 0; jj < deg; jj++) {
    int s = row[jj];
    float lg = es[s * 4 + head] + edv;
    lg = lg >= 0.f ? lg : 0.2f * lg;
    m = fmaxf(m, lg);
  }
  float den = 0.f;
  float4 acc = make_float4(0.f, 0.f, 0.f, 0.f);
  for (int jj = 0; jj < deg; jj++) {
    int s = row[jj];
    float lg = es[s * 4 + head] + edv;
    lg = lg >= 0.f ? lg : 0.2f * lg;
    float wg = __expf(lg - m);
    den += wg;
    if (storemsg) {
      float4 x = ((const float4*)Wh)[(size_t)s * 64 + lane];
      acc.x += wg * x.x; acc.y += wg * x.y; acc.z += wg * x.z; acc.w += wg * x.w;
    }
  }
  float inv = 1.f / (den + 1e-9f);
  if (storemsg) {
    unsigned short h0,l0,h1,l1,h2,l2,h3,l3;
    splitbf(acc.x * inv, h0, l0); splitbf(acc.y * inv, h1, l1);
    splitbf(acc.z * inv, h2, l2); splitbf(acc.w * inv, h3, l3);
    int o = mrow * 256 + lane * 4;
    *(uint2*)(mbh + o) = pack4(h0, h1, h2, h3);
    *(uint2*)(mbl + o) = pack4(l0, l1, l2, l3);
  }
  if (allnodes) {
    float val = den * inv;
    val += __shfl_xor(val, 16);
    val += __shfl_xor(val, 32);
    if (lane == 0) score[v] = 0.25f * val;
  }
}

// one block per (b,t): softmax over 128 node scores, then weighted mean of h
__global__ void k_pool(const float* __restrict__ score, const float* __restrict__ h,
                       float* __restrict__ pooled) {
  __shared__ float a[128];
  __shared__ float sinv;
  int bt = blockIdx.x;
  int base = bt * 128;
  int tid = threadIdx.x;
  if (tid < 128) a[tid] = score[base + tid];
  __syncthreads();
  if (tid == 0) {
    float mx = a[0];
    for (int n = 1; n < 128; n++) mx = fmaxf(mx, a[n]);
    float s = 0.f;
    for (int n = 0; n < 128; n++) { float e = __expf(a[n] - mx); a[n] = e; s += e; }
    sinv = 1.f / (s * 128.f);
  }
  __syncthreads();
  float acc = 0.f;
  for (int n = 0; n < 128; n++) acc += a[n] * h[(size_t)(base + n) * 256 + tid];
  pooled[bt * 256 + tid] = acc * sinv;
}

__global__ void k_out(const float* __restrict__ pooled, float* __restrict__ out) {
  int i = blockIdx.x * blockDim.x + threadIdx.x;
  if (i >= 8192) return;
  int spk = i >> 12, b = (i >> 8) & 15, c = i & 255;
  float s = 0.f;
  for (int t = spk; t < 6; t += 2) s += pooled[(b * 6 + t) * 256 + c];
  out[i] = s;
}

extern "C" void kernel_launch(void* const* d_in, const int* in_sizes, int n_in,
                              void* d_out, int out_size, void* d_ws, size_t ws_size,
                              hipStream_t stream) {
  const float* emb    = (const float*)d_in[0];
  const float* nmask  = (const float*)d_in[1];
  const float* W      = (const float*)d_in[2];
  const float* a_src  = (const float*)d_in[3];
  const float* a_dst  = (const float*)d_in[4];
  const float* Wz     = (const float*)d_in[5];
  const float* Uz     = (const float*)d_in[6];
  const float* Wr     = (const float*)d_in[7];
  const float* Ur     = (const float*)d_in[8];
  const float* Wn     = (const float*)d_in[9];
  const float* Un     = (const float*)d_in[10];
  const float* bz     = (const float*)d_in[11];
  const float* br     = (const float*)d_in[12];
  const float* bn     = (const float*)d_in[13];
  const int* nodeidx  = (const int*)d_in[14];
  const int* esrc     = (const int*)d_in[15];
  const int* edst     = (const int*)d_in[16];
  float* out = (float*)d_out;

  char* ws = (char*)d_ws;
  size_t off = 0;
  auto carve = [&](size_t bytes) { char* p = ws + off; off += (bytes + 255) & ~(size_t)255; return p; };
  float* h      = (float*)carve(NTOT * 256 * 4);            // 12.6 MB
  float* Wh     = (float*)carve(NTOT * 256 * 4);            // 12.6 MB
  unsigned short* hbh = (unsigned short*)carve(NTOT * 256 * 2);   // 6.3 MB
  unsigned short* hbl = (unsigned short*)carve(NTOT * 256 * 2);   // 6.3 MB
  unsigned short* mbh = (unsigned short*)carve(2048 * 256 * 2);   // 1 MB
  unsigned short* mbl = (unsigned short*)carve(2048 * 256 * 2);
  unsigned short* rbh = (unsigned short*)carve(2048 * 256 * 2);
  unsigned short* rbl = (unsigned short*)carve(2048 * 256 * 2);
  float* es     = (float*)carve(NTOT * 4 * 4);
  float* ed     = (float*)carve(NTOT * 4 * 4);
  float* g1     = (float*)carve(2048 * 512 * 4);            // 4 MB (zpre | npre)
  float* uacc   = (float*)carve(6144 * 512 * 4);            // 12.6 MB
  float* score  = (float*)carve(NTOT * 4);
  float* pooled = (float*)carve(96 * 256 * 4);
  int*   cnt    = (int*)carve(NTOT * 4);
  unsigned short* adj = (unsigned short*)carve((size_t)NTOT * MAXDEG * 2);  // 1.57 MB
  unsigned short* wth = (unsigned short*)carve(1792 * 256 * 2);             // 0.9 MB
  unsigned short* wtl = (unsigned short*)carve(1792 * 256 * 2);
  if (off > ws_size) return;  // fail cleanly if workspace too small

  hipMemsetAsync(cnt, 0, NTOT * 4, stream);
  k_prep<<<5632, 256, 0, stream>>>(emb, nmask, nodeidx, W, Wz, Wr, Wn, Uz, Ur, Un,
                                   esrc, edst, cnt, h, hbh, hbl, wth, wtl, adj);
  // full Wh + es/ed (blocks 0..767) and uacc batch 0 (blocks 768..1535)
  k_mf<5><<<1536, 256, 0, stream>>>(hbh, hbl, wth, wtl, Wh, h, hbh, hbl, g1, uacc,
                                    rbh, rbl, bz, br, bn, a_src, a_dst, es, ed, 0);

  for (int t = 0; t < 6; t++) {
    if (t > 0) {
      // refresh Wh/es/ed for rows changed by last turn's GRU (turn t-1)
      k_mf<1><<<128, 256, 0, stream>>>(hbh, hbl, wth, wtl, Wh, h, hbh, hbl, g1, uacc,
                                       rbh, rbl, bz, br, bn, a_src, a_dst, es, ed, t - 1);
    }
    if (t < 5)
      k_attn<<<512, 256, 0, stream>>>(cnt, adj, es, ed, Wh, mbh, mbl, score, t, 0);
    else
      k_attn<<<3072, 256, 0, stream>>>(cnt, adj, es, ed, Wh, mbh, mbl, score, t, 1);
    k_mf<2><<<384, 256, 0, stream>>>(mbh, mbl, wth, wtl, Wh, h, hbh, hbl, g1, uacc,
                                     rbh, rbl, bz, br, bn, a_src, a_dst, es, ed, t);
    k_mf<3><<<128, 256, 0, stream>>>(rbh, rbl, wth, wtl, Wh, h, hbh, hbl, g1, uacc,
                                     rbh, rbl, bz, br, bn, a_src, a_dst, es, ed, t);
    if (t == 2) {
      // uacc batch 1: turns 3-5 (their h rows still untouched)
      k_mf<4><<<768, 256, 0, stream>>>(hbh, hbl, wth, wtl, Wh, h, hbh, hbl, g1, uacc,
                                       rbh, rbl, bz, br, bn, a_src, a_dst, es, ed, 1);
    }
  }

  k_pool<<<96, 256, 0, stream>>>(score, h, pooled);
  k_out<<<32, 256, 0, stream>>>(pooled, out);
}